// Round 10
// baseline (607.302 us; speedup 1.0000x reference)
//
#include <hip/hip_runtime.h>
#include <hip/hip_bf16.h>
#include <stdint.h>

// ---------------------------------------------------------------------------
// Mlp_cnn_shift: B=2 T=8 H=56 W=56 C=512 HID=1024, N = 50176 tokens
//  xb   = bf16(x)                                   [N,512]
//  GEMM1: xh = gelu(xb@fc_w+b)                      (plain store)
//  GEMM2: hs = inv-shift scatter of gelu(SHIFT(xh)@fc1_w+b); fused s0 sum
//         SHIFT(xh) gathered on the fly during A-staging (xs never exists)
//  GEMM3: w  = gelu(xh@fc2_w+b); fused s1 sum
//  tiny MLP + pairwise softmax -> a0,a1 (fp32 exact)
//  combine: hw = hs*a0 + w*a1 (shift-free, 16B vectorized)
//  GEMM4: out = hw @ proj_w + proj_b (fp32)
// hs boundary holes pre-zeroed by zero_holes (3.5% strips).
//
// R10 = R9 (best, 575us) + counted-vmcnt pipeline extended to GEMM2's SHIFTA:
//  * gather fast path made BRANCHLESS: unconditional uint4 load from clamped
//    row (unshifted row always valid) + AND-mask zero -> every thread issues
//    exactly 2 top-level gather loads/tile; rare 114-boundary branch only
//    ADDS guarded loads (count-safe: extra loads make vmcnt(4) stricter).
//  * per iter: gather(t+1) regs FIRST, B global_load_lds(t+1) LAST, ds_write
//    tile-t A-regs, s_waitcnt vmcnt(4) lgkmcnt(0) (tile-t's B+gather done,
//    tile-t+1's 4 stay in flight), s_barrier, ds_read+MFMA, barrier.
//  GEMM1/3/4 loops verbatim R9 (proven counted-vmcnt form).
// ---------------------------------------------------------------------------

typedef __attribute__((ext_vector_type(8))) short short8;
typedef __attribute__((ext_vector_type(4))) float floatx4;
typedef unsigned int uint;
typedef unsigned short ushort;

#define NTOK   50176
#define HWIMG  3136    // 56*56

// exact gelu (tiny MLP only)
__device__ __forceinline__ float gelu_exact(float v) {
    return 0.5f * v * (1.0f + erff(v * 0.70710678118654752440f));
}
// tanh-approx gelu = v * sigmoid(2u), u = 0.79788456*(v + 0.044715 v^3)
// max abs err ~3e-4; used for the 102.8M big-GEMM activations
__device__ __forceinline__ float gelu_fast(float v) {
    float u = v * (0.7978845608f + 0.0356774081f * v * v);
    return v * __builtin_amdgcn_rcpf(1.0f + __expf(-2.0f * u));
}

// shifts: g in 0..8 -> (1-g/3, 1-g%3) matches SHIFTS table
__device__ __forceinline__ int shift_h(int g) { return 1 - g / 3; }
__device__ __forceinline__ int shift_w(int g) { return 1 - g % 3; }

// ---- async global->LDS, 16B per lane ---------------------------------------
typedef const __attribute__((address_space(1))) uint* gas_ptr;
typedef __attribute__((address_space(3))) uint* las_ptr;

__device__ __forceinline__ void async_copy16(const void* g, void* l) {
    gas_ptr gp = (gas_ptr)(uintptr_t)g;
    las_ptr lp = (las_ptr)(uint32_t)(uintptr_t)l;
    __builtin_amdgcn_global_load_lds(gp, lp, 16, 0, 0);
}

// ---- GEMM: C[M,N] = act(A[M,K] @ Bt[N,K]^T + bias) -------------------------
// BM=BN=128, BK=32, 256 thr = 4 waves (2x2), wave 64x64 via 4x4 mfma 16x16x32.
// Both paths: double-buffered LDS, counted-vmcnt pipeline (see header).
// EPI: 0 = fp32 plain store (GEMM4)
//      1 = gelu bf16 plain store (GEMM1)
//      2 = gelu bf16 inverse-shift scatter ONLY + fused sum -> ssum (GEMM2)
//      3 = gelu bf16 plain store + fused sum -> ssum (GEMM3)
template <int EPI, bool SHIFTA>
__global__ __launch_bounds__(256) void gemm_bt(
    const __hip_bfloat16* __restrict__ A,
    const __hip_bfloat16* __restrict__ Bt,
    const float* __restrict__ bias,
    void* __restrict__ Cout,
    float* __restrict__ ssum, int N, int K)
{
    __shared__ __align__(16) __hip_bfloat16 As[2 * 128 * 32];
    __shared__ __align__(16) __hip_bfloat16 Bs[2 * 128 * 32];

    const int t    = threadIdx.x;
    const int lane = t & 63;
    const int wave = t >> 6;
    const int wm   = wave >> 1;
    const int wn   = wave & 1;

    // XCD swizzle: round-robin dispatch puts flat%8 on XCD flat&7; give each
    // XCD a contiguous bm range so its private L2 keeps the A-tiles.
    const int nbn  = gridDim.x;
    const int flat = blockIdx.y * nbn + blockIdx.x;
    const int xcd  = flat & 7;
    const int j    = flat >> 3;
    const int jd   = j / nbn;
    const int bm   = xcd * 49 + jd;
    const int bn   = j - jd * nbn;

    const int ar0 = bm * 128 + (t >> 2);   // A row staged at As[t*8]
    const int ar1 = ar0 + 64;              // A row staged at As[t*8+2048]
    const int ac  = (t & 3) * 8;           // channel base of this thread's chunk

    const __hip_bfloat16* ga0 = A  + (size_t)ar0 * K + ac;
    const __hip_bfloat16* ga1 = ga0 + (size_t)64 * K;
    const __hip_bfloat16* gb0 = Bt + (size_t)(bn * 128 + (t >> 2)) * K + ac;
    const __hip_bfloat16* gb1 = gb0 + (size_t)64 * K;

    floatx4 acc[4][4] = {};

    const int kq = (lane >> 4) * 8;
    const int ml = lane & 15;

    if constexpr (!SHIFTA) {
        // ---- counted-vmcnt double-buffered pipeline (verbatim R9) ----------
        auto stage = [&](int buf) {
            __hip_bfloat16* lA = &As[buf * 4096 + t * 8];
            __hip_bfloat16* lB = &Bs[buf * 4096 + t * 8];
            async_copy16(ga0, lA);
            async_copy16(ga1, lA + 2048);
            async_copy16(gb0, lB);
            async_copy16(gb1, lB + 2048);
            ga0 += 32; ga1 += 32; gb0 += 32; gb1 += 32;
        };

        const int nt = K >> 5;
        stage(0);                           // 4 loads in flight
        for (int tt = 0; tt < nt; ++tt) {
            const int cur = tt & 1;
            if (tt + 1 < nt) {
                stage(cur ^ 1);             // 8 in flight
                asm volatile("s_waitcnt vmcnt(4)" ::: "memory");  // tile-t done
            } else {
                asm volatile("s_waitcnt vmcnt(0)" ::: "memory");  // epilogue tile
            }
            __builtin_amdgcn_s_barrier();   // all waves' tile-t data in LDS
            asm volatile("" ::: "memory");  // no ds_read hoisting above barrier

            const int ab = cur * 4096;
            short8 af[4], bf[4];
#pragma unroll
            for (int i = 0; i < 4; i++) {
                af[i] = *(const short8*)&As[ab + (wm * 64 + i * 16 + ml) * 32 + kq];
                bf[i] = *(const short8*)&Bs[ab + (wn * 64 + i * 16 + ml) * 32 + kq];
            }
#pragma unroll
            for (int mi = 0; mi < 4; mi++)
#pragma unroll
                for (int ni = 0; ni < 4; ni++)
                    acc[mi][ni] = __builtin_amdgcn_mfma_f32_16x16x32_bf16(
                        af[mi], bf[ni], acc[mi][ni], 0, 0, 0);

            asm volatile("" ::: "memory");  // no ds_read sinking below barrier
            __builtin_amdgcn_s_barrier();   // reads retired before re-stage
        }
    } else {
        // ---- SHIFTA counted pipeline: reg-gather A + global_load_lds B -----
        // image coordinates of the two staged rows
        const int rem0 = ar0 % HWIMG, rem1 = ar1 % HWIMG;
        const int oh0 = rem0 / 56, ow0 = rem0 - oh0 * 56;
        const int oh1 = rem1 / 56, ow1 = rem1 - oh1 * 56;

        // branchless fast gather: 2 top-level unconditional uint4 loads/tile
        // (clamped row when out-of-image + AND-mask zero); rare 114-boundary
        // branch only ADDS guarded loads (vmcnt(4) stays correct).
        auto gather = [&](int k0, uint4& o0, uint4& o1) {
            const int c0 = k0 + ac;
            const int gl = c0 / 114;
            const int gh = (c0 + 7) / 114;
            const int shl = shift_h(gl), swl = shift_w(gl);
            const int offl = shl * 56 + swl;
            const bool v0 = ((unsigned)(oh0 - shl) < 56u) & ((unsigned)(ow0 - swl) < 56u);
            const bool v1 = ((unsigned)(oh1 - shl) < 56u) & ((unsigned)(ow1 - swl) < 56u);
            const uint4 l0 = *(const uint4*)(A + (size_t)(ar0 - (v0 ? offl : 0)) * K + c0);
            const uint4 l1 = *(const uint4*)(A + (size_t)(ar1 - (v1 ? offl : 0)) * K + c0);
            const uint m0 = v0 ? 0xffffffffu : 0u;
            const uint m1 = v1 ? 0xffffffffu : 0u;
            o0.x = l0.x & m0; o0.y = l0.y & m0; o0.z = l0.z & m0; o0.w = l0.w & m0;
            o1.x = l1.x & m1; o1.y = l1.y & m1; o1.z = l1.z & m1; o1.w = l1.w & m1;
            if (gl != gh) {                  // rare: 114-boundary inside chunk
                union { ushort us[8]; uint4 v; } p0, p1;
#pragma unroll
                for (int e = 0; e < 8; e++) {
                    const int c  = c0 + e;
                    const int gg = c / 114;
                    const int sh = shift_h(gg), sw = shift_w(gg);
                    const int off = sh * 56 + sw;
                    ushort a0v = 0, a1v = 0;
                    if ((unsigned)(oh0 - sh) < 56u && (unsigned)(ow0 - sw) < 56u)
                        a0v = *(const ushort*)(A + (size_t)(ar0 - off) * K + c);
                    if ((unsigned)(oh1 - sh) < 56u && (unsigned)(ow1 - sw) < 56u)
                        a1v = *(const ushort*)(A + (size_t)(ar1 - off) * K + c);
                    p0.us[e] = a0v; p1.us[e] = a1v;
                }
                o0 = p0.v; o1 = p1.v;
            }
        };
        auto stageB = [&](int buf) {
            __hip_bfloat16* lB = &Bs[buf * 4096 + t * 8];
            async_copy16(gb0, lB);
            async_copy16(gb1, lB + 2048);
            gb0 += 32; gb1 += 32;
        };

        const int nt = K >> 5;
        uint4 pa0, pa1;
        gather(0, pa0, pa1);                // >=2 reg loads in flight
        stageB(0);                          // +2 lds loads

        for (int tt = 0; tt < nt; ++tt) {
            const int cur = tt & 1;
            uint4 na0, na1;
            if (tt + 1 < nt) {
                gather((tt + 1) * 32, na0, na1);   // >=2 loads, issued FIRST
                stageB(cur ^ 1);                    // exactly 2, issued LAST
            }
            // tile-t A regs -> LDS (compiler auto-waits pa0/pa1's loads)
            *(uint4*)&As[cur * 4096 + t * 8]        = pa0;
            *(uint4*)&As[cur * 4096 + t * 8 + 2048] = pa1;
            if (tt + 1 < nt)
                asm volatile("s_waitcnt vmcnt(4) lgkmcnt(0)" ::: "memory");
            else
                asm volatile("s_waitcnt vmcnt(0) lgkmcnt(0)" ::: "memory");
            __builtin_amdgcn_s_barrier();   // tile-t A+B visible to all waves
            asm volatile("" ::: "memory");

            const int ab = cur * 4096;
            short8 af[4], bf[4];
#pragma unroll
            for (int i = 0; i < 4; i++) {
                af[i] = *(const short8*)&As[ab + (wm * 64 + i * 16 + ml) * 32 + kq];
                bf[i] = *(const short8*)&Bs[ab + (wn * 64 + i * 16 + ml) * 32 + kq];
            }
#pragma unroll
            for (int mi = 0; mi < 4; mi++)
#pragma unroll
                for (int ni = 0; ni < 4; ni++)
                    acc[mi][ni] = __builtin_amdgcn_mfma_f32_16x16x32_bf16(
                        af[mi], bf[ni], acc[mi][ni], 0, 0, 0);

            asm volatile("" ::: "memory");
            __builtin_amdgcn_s_barrier();   // reads retired before re-stage
            pa0 = na0; pa1 = na1;
        }
    }

    // epilogue: C/D layout col = lane&15, row = (lane>>4)*4 + reg (m89)
    const int rq = (lane >> 4) * 4;

    int cols[4], gsh[4], gsw[4];
    float bv[4];
    float sum[4] = {0.f, 0.f, 0.f, 0.f};
#pragma unroll
    for (int ni = 0; ni < 4; ni++) {
        const int col = bn * 128 + wn * 64 + ni * 16 + ml;
        cols[ni] = col;
        bv[ni] = bias[col];
        if (EPI == 2) { const int g = col / 57; gsh[ni] = shift_h(g); gsw[ni] = shift_w(g); }
    }

#pragma unroll
    for (int mi = 0; mi < 4; mi++) {
        const int row0 = bm * 128 + wm * 64 + mi * 16 + rq;
        int phr[4], pwr[4];
        if (EPI == 2) {
            const int bt_ = row0 / HWIMG;
            const int rem = row0 - bt_ * HWIMG;
            const int ph0 = rem / 56;
            const int pw0 = rem - ph0 * 56;
#pragma unroll
            for (int r = 0; r < 4; r++) {
                int pw = pw0 + r, ph = ph0;
                if (pw >= 56) { pw -= 56; ph += 1; }
                if (ph >= 56) { ph = 0; }
                phr[r] = ph; pwr[r] = pw;
            }
        }
#pragma unroll
        for (int ni = 0; ni < 4; ni++) {
            const int col = cols[ni];
#pragma unroll
            for (int r = 0; r < 4; r++) {
                const int tok = row0 + r;
                float v = acc[mi][ni][r] + bv[ni];
                if (EPI != 0) v = gelu_fast(v);
                if (EPI == 0) {
                    ((float*)Cout)[(size_t)tok * N + col] = v;
                } else if (EPI == 1) {
                    ((__hip_bfloat16*)Cout)[(size_t)tok * N + col] = __float2bfloat16(v);
                } else if (EPI == 2) {
                    const int th = phr[r] - gsh[ni], tw = pwr[r] - gsw[ni];
                    if ((unsigned)th < 56u && (unsigned)tw < 56u) {
                        ((__hip_bfloat16*)Cout)[(size_t)(tok - gsh[ni] * 56 - gsw[ni]) * N + col]
                            = __float2bfloat16(v);
                        sum[ni] += v;
                    }
                } else {
                    ((__hip_bfloat16*)Cout)[(size_t)tok * N + col] = __float2bfloat16(v);
                    sum[ni] += v;
                }
            }
        }
    }

    if (EPI == 2 || EPI == 3) {
        const int b = (bm >= 196) ? 1 : 0;   // token 25088 = block 196 boundary
#pragma unroll
        for (int ni = 0; ni < 4; ni++) {
            float s = sum[ni];
            s += __shfl_xor(s, 16, 64);
            s += __shfl_xor(s, 32, 64);
            if (lane < 16) atomicAdd(&ssum[b * 512 + cols[ni]], s);
        }
    }
}

// ---- zero the shift boundary holes (frame strips only, ~3.5%) --------------
// buf[bt,oh,ow,c] is a hole iff source (ih=oh-SGN*sh, iw=ow-SGN*sw) out of range.
// hs: SGN=-1 (hs[o]=hpre[o+s]).
template <int C, int GS, int SGN>
__global__ __launch_bounds__(256) void zero_holes(__hip_bfloat16* __restrict__ buf)
{
    const int i = blockIdx.x * 256 + threadIdx.x;   // 16*220*C exact
    const int c = i % C;
    const int p = i / C;
    const int bt = p / 220, fp = p % 220;
    int oh, ow;
    if (fp < 56)       { oh = 0;        ow = fp; }
    else if (fp < 112) { oh = 55;       ow = fp - 56; }
    else if (fp < 166) { oh = fp - 111; ow = 0; }
    else               { oh = fp - 165; ow = 55; }
    const int g = c / GS;
    const int ih = oh - SGN * shift_h(g);
    const int iw = ow - SGN * shift_w(g);
    if ((unsigned)ih >= 56u || (unsigned)iw >= 56u)
        buf[((size_t)(bt * HWIMG + oh * 56 + ow)) * C + c] = __float2bfloat16(0.0f);
}

// ---- prep: x fp32 -> bf16 ---------------------------------------------------
__global__ __launch_bounds__(256) void cvt_x(const float4* __restrict__ x,
                                             __hip_bfloat16* __restrict__ xb)
{
    int i = blockIdx.x * 256 + threadIdx.x;
    float4 v = x[i];
    __hip_bfloat16 b0 = __float2bfloat16(v.x);
    __hip_bfloat16 b1 = __float2bfloat16(v.y);
    __hip_bfloat16 b2 = __float2bfloat16(v.z);
    __hip_bfloat16 b3 = __float2bfloat16(v.w);
    uint2 o;
    o.x = (uint)*(ushort*)&b0 | ((uint)*(ushort*)&b1 << 16);
    o.y = (uint)*(ushort*)&b2 | ((uint)*(ushort*)&b3 << 16);
    *(uint2*)&xb[(size_t)i * 4] = o;
}

// ---- prep: transpose + convert the 4 weight matrices to bf16 Bt layout -----
__global__ __launch_bounds__(256) void prep_w(
    const float* __restrict__ fcw,  const float* __restrict__ fc1w,
    const float* __restrict__ fc2w, const float* __restrict__ projw,
    __hip_bfloat16* __restrict__ fcwT, __hip_bfloat16* __restrict__ fc1T,
    __hip_bfloat16* __restrict__ fc2T, __hip_bfloat16* __restrict__ projT)
{
    int i = blockIdx.x * 256 + threadIdx.x;
    if (i < 524288) {                       // fc_w [512,1024] -> [1024,512]
        int n = i >> 9, k = i & 511;
        fcwT[i] = __float2bfloat16(fcw[k * 1024 + n]);
    } else if (i < 1048576) {               // fc1_w [1024,512] -> [512,1024]
        int j = i - 524288;
        int n = j >> 10, k = j & 1023;
        fc1T[j] = __float2bfloat16(fc1w[k * 512 + n]);
    } else if (i < 1572864) {               // fc2_w [1024,512] -> [512,1024]
        int j = i - 1048576;
        int n = j >> 10, k = j & 1023;
        fc2T[j] = __float2bfloat16(fc2w[k * 512 + n]);
    } else if (i < 1835008) {               // proj_w [512,512] -> [512,512]
        int j = i - 1572864;
        int n = j >> 9, k = j & 511;
        projT[j] = __float2bfloat16(projw[k * 512 + n]);
    }
}

// ---- tiny squeeze-excite MLP + pairwise softmax, fp32 exact ----------------
__global__ __launch_bounds__(256) void tiny_mlp(
    const float* __restrict__ s0, const float* __restrict__ s1,
    const float* __restrict__ rw1_w, const float* __restrict__ rw1_b,
    const float* __restrict__ rw2_w, const float* __restrict__ rw2_b,
    float* __restrict__ a0, float* __restrict__ a1)
{
    __shared__ float mean[1024];   // [2][512]
    __shared__ float z[256];       // [2][128]
    __shared__ float av[2048];     // [2][1024]
    const int t = threadIdx.x;
    for (int i = t; i < 1024; i += 256)
        mean[i] = (s0[i] + s1[i]) * (1.0f / 25088.0f);
    __syncthreads();
    {
        const int b = t >> 7, j = t & 127;
        float acc = rw1_b[j];
        for (int cc = 0; cc < 512; cc++)
            acc += mean[b * 512 + cc] * rw1_w[cc * 128 + j];
        z[t] = gelu_exact(acc);
    }
    __syncthreads();
    for (int i = t; i < 2048; i += 256) {
        const int b = i >> 10, o = i & 1023;
        float acc = rw2_b[o];
        for (int j = 0; j < 128; j++)
            acc += z[b * 128 + j] * rw2_w[j * 1024 + o];
        av[i] = acc;
    }
    __syncthreads();
    for (int i = t; i < 1024; i += 256) {
        const int b = i >> 9, cc = i & 511;
        const float x0 = av[b * 1024 + 2 * cc];
        const float x1 = av[b * 1024 + 2 * cc + 1];
        const float m = fmaxf(x0, x1);
        const float e0 = expf(x0 - m), e1 = expf(x1 - m);
        const float inv = 1.0f / (e0 + e1);
        a0[i] = e0 * inv;
        a1[i] = e1 * inv;
    }
}

// ---- hw = hs*a0 + w*a1 (shift-free, 8 channels / thread) --------------------
__device__ __forceinline__ float bf_lo(uint u) { return __uint_as_float(u << 16); }
__device__ __forceinline__ float bf_hi(uint u) { return __uint_as_float(u & 0xffff0000u); }
__device__ __forceinline__ uint pack_bf2(float lo, float hi) {
    __hip_bfloat16 a = __float2bfloat16(lo), b = __float2bfloat16(hi);
    return (uint)*(ushort*)&a | ((uint)*(ushort*)&b << 16);
}

__global__ __launch_bounds__(256) void combine(
    const uint4* __restrict__ hs4, const uint4* __restrict__ w4,
    const float* __restrict__ a0, const float* __restrict__ a1,
    uint4* __restrict__ hw4)
{
    const int i = blockIdx.x * 256 + threadIdx.x;   // 3,211,264 exact
    const int ck = i & 63;                          // 8-channel chunk
    const int tok = i >> 6;
    const int b = (tok >= 25088) ? 1 : 0;
    const float4* A0 = (const float4*)&a0[b * 512 + ck * 8];
    const float4* A1 = (const float4*)&a1[b * 512 + ck * 8];
    const float4 s0l = A0[0], s0h = A0[1];
    const float4 s1l = A1[0], s1h = A1[1];
    const uint4 h = hs4[i], w = w4[i];
    uint4 o;
    o.x = pack_bf2(bf_lo(h.x) * s0l.x + bf_lo(w.x) * s1l.x,
                   bf_hi(h.x) * s0l.y + bf_hi(w.x) * s1l.y);
    o.y = pack_bf2(bf_lo(h.y) * s0l.z + bf_lo(w.y) * s1l.z,
                   bf_hi(h.y) * s0l.w + bf_hi(w.y) * s1l.w);
    o.z = pack_bf2(bf_lo(h.z) * s0h.x + bf_lo(w.z) * s1h.x,
                   bf_hi(h.z) * s0h.y + bf_hi(w.z) * s1h.y);
    o.w = pack_bf2(bf_lo(h.w) * s0h.z + bf_lo(w.w) * s1h.z,
                   bf_hi(h.w) * s0h.w + bf_hi(w.w) * s1h.w);
    hw4[i] = o;
}

// ---------------------------------------------------------------------------
extern "C" void kernel_launch(void* const* d_in, const int* in_sizes, int n_in,
                              void* d_out, int out_size, void* d_ws, size_t ws_size,
                              hipStream_t stream)
{
    const float* x      = (const float*)d_in[0];
    const float* fc_w   = (const float*)d_in[1];
    const float* fc_b   = (const float*)d_in[2];
    const float* fc1_w  = (const float*)d_in[3];
    const float* fc1_b  = (const float*)d_in[4];
    const float* fc2_w  = (const float*)d_in[5];
    const float* fc2_b  = (const float*)d_in[6];
    const float* rw1_w  = (const float*)d_in[7];
    const float* rw1_b  = (const float*)d_in[8];
    const float* rw2_w  = (const float*)d_in[9];
    const float* rw2_b  = (const float*)d_in[10];
    const float* proj_w = (const float*)d_in[11];
    const float* proj_b = (const float*)d_in[12];

    uint8_t* ws = (uint8_t*)d_ws;
    __hip_bfloat16* xh  = (__hip_bfloat16*)(ws);                    // [N,1024] bf16, later hw
    __hip_bfloat16* xb  = (__hip_bfloat16*)(ws + 102760448);        // [N,512] bf16, later hs
    uint8_t* wt         = ws + 102760448 + 51380224;
    __hip_bfloat16* fcwT  = (__hip_bfloat16*)(wt);
    __hip_bfloat16* fc1T  = fcwT + 524288;
    __hip_bfloat16* fc2T  = fc1T + 524288;
    __hip_bfloat16* projT = fc2T + 524288;
    float* s0 = (float*)(wt + 3670016);
    float* s1 = s0 + 1024;
    float* a0 = s1 + 1024;
    float* a1 = a0 + 1024;

    __hip_bfloat16* wbuf = (__hip_bfloat16*)d_out;  // [N,512]  bf16 (dead after combine)
    __hip_bfloat16* hs   = xb;                      // [N,512]  bf16 (xb dead after GEMM1)
    __hip_bfloat16* hw   = xh;                      // [N,512]  bf16 (xh dead after GEMM3)

    hipMemsetAsync(s0, 0, 8192, stream);            // zero s0,s1

    cvt_x<<<25088, 256, 0, stream>>>((const float4*)x, xb);
    prep_w<<<7168, 256, 0, stream>>>(fc_w, fc1_w, fc2_w, proj_w, fcwT, fc1T, fc2T, projT);

    // GEMM1: xh = gelu(xb@fc_w+b) (plain store; shift gathered by GEMM2)
    gemm_bt<1, false><<<dim3(8, 392), 256, 0, stream>>>(xb, fcwT, fc_b, xh, nullptr, 1024, 512);
    // hs boundary holes (hs aliases xb -> must run after GEMM1)
    zero_holes<512, 57, -1><<<7040, 256, 0, stream>>>(hs);
    // GEMM2: hs = inv-shift scatter of gelu(SHIFT(xh)@fc1_w+b); fused s0
    gemm_bt<2, true><<<dim3(4, 392), 256, 0, stream>>>(xh, fc1T, fc1_b, hs, s0, 512, 1024);
    // GEMM3: w = gelu(xh@fc2_w+b) -> d_out; fused s1
    gemm_bt<3, false><<<dim3(4, 392), 256, 0, stream>>>(xh, fc2T, fc2_b, wbuf, s1, 512, 1024);
    // tiny MLP + softmax -> a0,a1
    tiny_mlp<<<1, 256, 0, stream>>>(s0, s1, rw1_w, rw1_b, rw2_w, rw2_b, a0, a1);
    // hw = hs*a0 + w*a1 -> xh region
    combine<<<12544, 256, 0, stream>>>((const uint4*)hs, (const uint4*)wbuf, a0, a1, (uint4*)hw);
    // GEMM4: out = hw @ proj_w + proj_b, fp32 -> d_out
    gemm_bt<0, false><<<dim3(4, 392), 256, 0, stream>>>(hw, projT, proj_b, d_out, nullptr, 512, 512);
}

// Round 12
// 566.228 us; speedup vs baseline: 1.0725x; 1.0725x over previous
//
#include <hip/hip_runtime.h>
#include <hip/hip_bf16.h>
#include <stdint.h>

// ---------------------------------------------------------------------------
// Mlp_cnn_shift: B=2 T=8 H=56 W=56 C=512 HID=1024, N = 50176 tokens
//  xb   = bf16(x)                                   [N,512]
//  GEMM1: xh = gelu(xb@fc_w+b)                      (plain store)
//  GEMM2: hs = inv-shift scatter of gelu(SHIFT(xh)@fc1_w+b); fused s0 sum
//         SHIFT(xh) realized as per-lane shifted SOURCE address on
//         global_load_lds (LDS dest linear; global src per-lane, m173
//         pattern); out-of-image rows read a zero page.
//  GEMM3: w  = gelu(xh@fc2_w+b); fused s1 sum
//  tiny MLP + pairwise softmax -> a0,a1 (fp32 exact)
//  combine: hw = hs*a0 + w*a1 (shift-free, 16B vectorized)
//  GEMM4: out = hw @ proj_w + proj_b (fp32)
// hs boundary holes pre-zeroed by zero_holes (3.5% strips).
//
// R12 = R11 with the zero page moved from workspace (possible 64B OOB — the
// likely cause of R11's container crash) to a zero-initialized __device__
// global (.bss, no memset, no workspace growth). Kernel logic unchanged:
//  * GEMM2 on the SAME counted-vmcnt global_load_lds pipeline as GEMM1/3/4.
//  * A-source per lane: valid ? &A[(ar-off(g))*K+c0] : zero-page.
//  * 114-boundary straddling chunks (~8 chunks total): gload zero page;
//    lo/hi row chunks reg-prefetched ONE ITER AHEAD (issued before gloads ->
//    complete at vmcnt(4)), mask-merged, ds_write_b128 after vmcnt wait.
// GEMM1/3/4 loops verbatim R9 (575us best; sentinels).
// ---------------------------------------------------------------------------

typedef __attribute__((ext_vector_type(8))) short short8;
typedef __attribute__((ext_vector_type(4))) float floatx4;
typedef unsigned int uint;
typedef unsigned short ushort;

#define NTOK   50176
#define HWIMG  3136    // 56*56

// 64B zero page for out-of-image / straddle gloads (.bss -> zeroed at load)
__device__ __align__(64) uint g_zpage[16];

// exact gelu (tiny MLP only)
__device__ __forceinline__ float gelu_exact(float v) {
    return 0.5f * v * (1.0f + erff(v * 0.70710678118654752440f));
}
// tanh-approx gelu = v * sigmoid(2u), u = 0.79788456*(v + 0.044715 v^3)
// max abs err ~3e-4; used for the 102.8M big-GEMM activations
__device__ __forceinline__ float gelu_fast(float v) {
    float u = v * (0.7978845608f + 0.0356774081f * v * v);
    return v * __builtin_amdgcn_rcpf(1.0f + __expf(-2.0f * u));
}

// shifts: g in 0..8 -> (1-g/3, 1-g%3) matches SHIFTS table
__device__ __forceinline__ int shift_h(int g) { return 1 - g / 3; }
__device__ __forceinline__ int shift_w(int g) { return 1 - g % 3; }

// ---- async global->LDS, 16B per lane ---------------------------------------
typedef const __attribute__((address_space(1))) uint* gas_ptr;
typedef __attribute__((address_space(3))) uint* las_ptr;

__device__ __forceinline__ void async_copy16(const void* g, void* l) {
    gas_ptr gp = (gas_ptr)(uintptr_t)g;
    las_ptr lp = (las_ptr)(uint32_t)(uintptr_t)l;
    __builtin_amdgcn_global_load_lds(gp, lp, 16, 0, 0);
}

// ---- GEMM: C[M,N] = act(A[M,K] @ Bt[N,K]^T + bias) -------------------------
// BM=BN=128, BK=32, 256 thr = 4 waves (2x2), wave 64x64 via 4x4 mfma 16x16x32.
// Both paths: counted-vmcnt double-buffered global_load_lds pipeline.
// EPI: 0 = fp32 plain store (GEMM4)
//      1 = gelu bf16 plain store (GEMM1)
//      2 = gelu bf16 inverse-shift scatter ONLY + fused sum -> ssum (GEMM2)
//      3 = gelu bf16 plain store + fused sum -> ssum (GEMM3)
template <int EPI, bool SHIFTA>
__global__ __launch_bounds__(256) void gemm_bt(
    const __hip_bfloat16* __restrict__ A,
    const __hip_bfloat16* __restrict__ Bt,
    const float* __restrict__ bias,
    void* __restrict__ Cout,
    float* __restrict__ ssum, int N, int K)
{
    __shared__ __align__(16) __hip_bfloat16 As[2 * 128 * 32];
    __shared__ __align__(16) __hip_bfloat16 Bs[2 * 128 * 32];

    const int t    = threadIdx.x;
    const int lane = t & 63;
    const int wave = t >> 6;
    const int wm   = wave >> 1;
    const int wn   = wave & 1;

    // XCD swizzle: round-robin dispatch puts flat%8 on XCD flat&7; give each
    // XCD a contiguous bm range so its private L2 keeps the A-tiles.
    const int nbn  = gridDim.x;
    const int flat = blockIdx.y * nbn + blockIdx.x;
    const int xcd  = flat & 7;
    const int j    = flat >> 3;
    const int jd   = j / nbn;
    const int bm   = xcd * 49 + jd;
    const int bn   = j - jd * nbn;

    const int ar0 = bm * 128 + (t >> 2);   // A row staged at As[t*8]
    const int ar1 = ar0 + 64;              // A row staged at As[t*8+2048]
    const int ac  = (t & 3) * 8;           // channel base of this thread's chunk

    const __hip_bfloat16* ga0 = A  + (size_t)ar0 * K + ac;
    const __hip_bfloat16* ga1 = ga0 + (size_t)64 * K;
    const __hip_bfloat16* gb0 = Bt + (size_t)(bn * 128 + (t >> 2)) * K + ac;
    const __hip_bfloat16* gb1 = gb0 + (size_t)64 * K;

    floatx4 acc[4][4] = {};

    const int kq = (lane >> 4) * 8;
    const int ml = lane & 15;

    if constexpr (!SHIFTA) {
        // ---- counted-vmcnt double-buffered pipeline (verbatim R9) ----------
        auto stage = [&](int buf) {
            __hip_bfloat16* lA = &As[buf * 4096 + t * 8];
            __hip_bfloat16* lB = &Bs[buf * 4096 + t * 8];
            async_copy16(ga0, lA);
            async_copy16(ga1, lA + 2048);
            async_copy16(gb0, lB);
            async_copy16(gb1, lB + 2048);
            ga0 += 32; ga1 += 32; gb0 += 32; gb1 += 32;
        };

        const int nt = K >> 5;
        stage(0);                           // 4 loads in flight
        for (int tt = 0; tt < nt; ++tt) {
            const int cur = tt & 1;
            if (tt + 1 < nt) {
                stage(cur ^ 1);             // 8 in flight
                asm volatile("s_waitcnt vmcnt(4)" ::: "memory");  // tile-t done
            } else {
                asm volatile("s_waitcnt vmcnt(0)" ::: "memory");  // epilogue tile
            }
            __builtin_amdgcn_s_barrier();   // all waves' tile-t data in LDS
            asm volatile("" ::: "memory");  // no ds_read hoisting above barrier

            const int ab = cur * 4096;
            short8 af[4], bf[4];
#pragma unroll
            for (int i = 0; i < 4; i++) {
                af[i] = *(const short8*)&As[ab + (wm * 64 + i * 16 + ml) * 32 + kq];
                bf[i] = *(const short8*)&Bs[ab + (wn * 64 + i * 16 + ml) * 32 + kq];
            }
#pragma unroll
            for (int mi = 0; mi < 4; mi++)
#pragma unroll
                for (int ni = 0; ni < 4; ni++)
                    acc[mi][ni] = __builtin_amdgcn_mfma_f32_16x16x32_bf16(
                        af[mi], bf[ni], acc[mi][ni], 0, 0, 0);

            asm volatile("" ::: "memory");  // no ds_read sinking below barrier
            __builtin_amdgcn_s_barrier();   // reads retired before re-stage
        }
    } else {
        // ---- SHIFTA counted pipeline: shift folded into gload SOURCE -------
        const int rem0 = ar0 % HWIMG, rem1 = ar1 % HWIMG;
        const int oh0 = rem0 / 56, ow0 = rem0 - oh0 * 56;
        const int oh1 = rem1 / 56, ow1 = rem1 - oh1 * 56;
        const __hip_bfloat16* zsrc = (const __hip_bfloat16*)g_zpage;

        // stage tile tx into buf. Uniform chunk: gload from shifted row (or
        // zero page if out-of-image). Straddling chunk: gload zero page +
        // reg-prefetch lo/hi row chunks (issued BEFORE gloads).
        auto stageS = [&](int buf, int tx, bool& strad,
                          uint4& lo0, uint4& hi0, uint4& lo1, uint4& hi1) {
            const int c0 = tx * 32 + ac;
            const int gl = c0 / 114;
            const int gh = (c0 + 7) / 114;
            const int shl = shift_h(gl), swl = shift_w(gl);
            const int offl = shl * 56 + swl;
            const bool v0 = ((unsigned)(oh0 - shl) < 56u) && ((unsigned)(ow0 - swl) < 56u);
            const bool v1 = ((unsigned)(oh1 - shl) < 56u) && ((unsigned)(ow1 - swl) < 56u);
            strad = (gl != gh);
            const __hip_bfloat16* p0 = zsrc;
            const __hip_bfloat16* p1 = zsrc;
            if (!strad) {
                if (v0) p0 = A + (size_t)(ar0 - offl) * K + c0;
                if (v1) p1 = A + (size_t)(ar1 - offl) * K + c0;
            } else {
                const int shh = shift_h(gh), swh = shift_w(gh);
                const int offh = shh * 56 + swh;
                const bool w0 = ((unsigned)(oh0 - shh) < 56u) && ((unsigned)(ow0 - swh) < 56u);
                const bool w1 = ((unsigned)(oh1 - shh) < 56u) && ((unsigned)(ow1 - swh) < 56u);
                lo0 = *(const uint4*)(A + (size_t)(ar0 - (v0 ? offl : 0)) * K + c0);
                hi0 = *(const uint4*)(A + (size_t)(ar0 - (w0 ? offh : 0)) * K + c0);
                lo1 = *(const uint4*)(A + (size_t)(ar1 - (v1 ? offl : 0)) * K + c0);
                hi1 = *(const uint4*)(A + (size_t)(ar1 - (w1 ? offh : 0)) * K + c0);
            }
            async_copy16(p0, &As[buf * 4096 + t * 8]);
            async_copy16(p1, &As[buf * 4096 + t * 8 + 2048]);
            async_copy16(gb0, &Bs[buf * 4096 + t * 8]);
            async_copy16(gb1, &Bs[buf * 4096 + t * 8 + 2048]);
            gb0 += 32; gb1 += 32;
        };

        // patch tile tx's straddling chunk in buf (regs complete: loaded one
        // iteration ago, older than tile-tx's gloads which vmcnt(4) drained).
        auto mergeS = [&](int buf, int tx,
                          const uint4& lo0, const uint4& hi0,
                          const uint4& lo1, const uint4& hi1) {
            const int c0 = tx * 32 + ac;
            const int gl = c0 / 114;
            const int gh = (c0 + 7) / 114;
            if (gl == gh) return;
            const int shl = shift_h(gl), swl = shift_w(gl);
            const int shh = shift_h(gh), swh = shift_w(gh);
            const bool v0 = ((unsigned)(oh0 - shl) < 56u) && ((unsigned)(ow0 - swl) < 56u);
            const bool v1 = ((unsigned)(oh1 - shl) < 56u) && ((unsigned)(ow1 - swl) < 56u);
            const bool w0 = ((unsigned)(oh0 - shh) < 56u) && ((unsigned)(ow0 - swh) < 56u);
            const bool w1 = ((unsigned)(oh1 - shh) < 56u) && ((unsigned)(ow1 - swh) < 56u);
            const int thr = (gl + 1) * 114 - c0;   // 1..7: elems < thr from lo
            const uint ml0 = v0 ? ~0u : 0u, mh0 = w0 ? ~0u : 0u;
            const uint ml1 = v1 ? ~0u : 0u, mh1 = w1 ? ~0u : 0u;
            auto mw = [&](uint lo, uint hi, uint mlo, uint mhi, int jb) -> uint {
                const uint l = lo & mlo, h = hi & mhi;
                const uint e0 = (jb < thr)     ? (l & 0xffffu)      : (h & 0xffffu);
                const uint e1 = (jb + 1 < thr) ? (l & 0xffff0000u)  : (h & 0xffff0000u);
                return e0 | e1;
            };
            uint4 m0, m1;
            m0.x = mw(lo0.x, hi0.x, ml0, mh0, 0);
            m0.y = mw(lo0.y, hi0.y, ml0, mh0, 2);
            m0.z = mw(lo0.z, hi0.z, ml0, mh0, 4);
            m0.w = mw(lo0.w, hi0.w, ml0, mh0, 6);
            m1.x = mw(lo1.x, hi1.x, ml1, mh1, 0);
            m1.y = mw(lo1.y, hi1.y, ml1, mh1, 2);
            m1.z = mw(lo1.z, hi1.z, ml1, mh1, 4);
            m1.w = mw(lo1.w, hi1.w, ml1, mh1, 6);
            *(uint4*)&As[buf * 4096 + t * 8]        = m0;
            *(uint4*)&As[buf * 4096 + t * 8 + 2048] = m1;
        };

        const int nt = K >> 5;
        uint4 plo0, phi0, plo1, phi1;
        bool strad0;
        stageS(0, 0, strad0, plo0, phi0, plo1, phi1);   // tile 0 never straddles

        for (int tt = 0; tt < nt; ++tt) {
            const int cur = tt & 1;
            uint4 nlo0, nhi0, nlo1, nhi1;
            bool nstrad = false;
            if (tt + 1 < nt) {
                stageS(cur ^ 1, tt + 1, nstrad, nlo0, nhi0, nlo1, nhi1);
                asm volatile("s_waitcnt vmcnt(4)" ::: "memory");  // tile-t landed
            } else {
                asm volatile("s_waitcnt vmcnt(0)" ::: "memory");
            }
            mergeS(cur, tt, plo0, phi0, plo1, phi1);    // overwrite after land
            asm volatile("s_waitcnt lgkmcnt(0)" ::: "memory");
            __builtin_amdgcn_s_barrier();
            asm volatile("" ::: "memory");

            const int ab = cur * 4096;
            short8 af[4], bf[4];
#pragma unroll
            for (int i = 0; i < 4; i++) {
                af[i] = *(const short8*)&As[ab + (wm * 64 + i * 16 + ml) * 32 + kq];
                bf[i] = *(const short8*)&Bs[ab + (wn * 64 + i * 16 + ml) * 32 + kq];
            }
#pragma unroll
            for (int mi = 0; mi < 4; mi++)
#pragma unroll
                for (int ni = 0; ni < 4; ni++)
                    acc[mi][ni] = __builtin_amdgcn_mfma_f32_16x16x32_bf16(
                        af[mi], bf[ni], acc[mi][ni], 0, 0, 0);

            asm volatile("" ::: "memory");
            __builtin_amdgcn_s_barrier();
            if (nstrad) { plo0 = nlo0; phi0 = nhi0; plo1 = nlo1; phi1 = nhi1; }
        }
    }

    // epilogue: C/D layout col = lane&15, row = (lane>>4)*4 + reg (m89)
    const int rq = (lane >> 4) * 4;

    int cols[4], gsh[4], gsw[4];
    float bv[4];
    float sum[4] = {0.f, 0.f, 0.f, 0.f};
#pragma unroll
    for (int ni = 0; ni < 4; ni++) {
        const int col = bn * 128 + wn * 64 + ni * 16 + ml;
        cols[ni] = col;
        bv[ni] = bias[col];
        if (EPI == 2) { const int g = col / 57; gsh[ni] = shift_h(g); gsw[ni] = shift_w(g); }
    }

#pragma unroll
    for (int mi = 0; mi < 4; mi++) {
        const int row0 = bm * 128 + wm * 64 + mi * 16 + rq;
        int phr[4], pwr[4];
        if (EPI == 2) {
            const int bt_ = row0 / HWIMG;
            const int rem = row0 - bt_ * HWIMG;
            const int ph0 = rem / 56;
            const int pw0 = rem - ph0 * 56;
#pragma unroll
            for (int r = 0; r < 4; r++) {
                int pw = pw0 + r, ph = ph0;
                if (pw >= 56) { pw -= 56; ph += 1; }
                if (ph >= 56) { ph = 0; }
                phr[r] = ph; pwr[r] = pw;
            }
        }
#pragma unroll
        for (int ni = 0; ni < 4; ni++) {
            const int col = cols[ni];
#pragma unroll
            for (int r = 0; r < 4; r++) {
                const int tok = row0 + r;
                float v = acc[mi][ni][r] + bv[ni];
                if (EPI != 0) v = gelu_fast(v);
                if (EPI == 0) {
                    ((float*)Cout)[(size_t)tok * N + col] = v;
                } else if (EPI == 1) {
                    ((__hip_bfloat16*)Cout)[(size_t)tok * N + col] = __float2bfloat16(v);
                } else if (EPI == 2) {
                    const int th = phr[r] - gsh[ni], tw = pwr[r] - gsw[ni];
                    if ((unsigned)th < 56u && (unsigned)tw < 56u) {
                        ((__hip_bfloat16*)Cout)[(size_t)(tok - gsh[ni] * 56 - gsw[ni]) * N + col]
                            = __float2bfloat16(v);
                        sum[ni] += v;
                    }
                } else {
                    ((__hip_bfloat16*)Cout)[(size_t)tok * N + col] = __float2bfloat16(v);
                    sum[ni] += v;
                }
            }
        }
    }

    if (EPI == 2 || EPI == 3) {
        const int b = (bm >= 196) ? 1 : 0;   // token 25088 = block 196 boundary
#pragma unroll
        for (int ni = 0; ni < 4; ni++) {
            float s = sum[ni];
            s += __shfl_xor(s, 16, 64);
            s += __shfl_xor(s, 32, 64);
            if (lane < 16) atomicAdd(&ssum[b * 512 + cols[ni]], s);
        }
    }
}

// ---- zero the shift boundary holes (frame strips only, ~3.5%) --------------
// buf[bt,oh,ow,c] is a hole iff source (ih=oh-SGN*sh, iw=ow-SGN*sw) out of range.
// hs: SGN=-1 (hs[o]=hpre[o+s]).
template <int C, int GS, int SGN>
__global__ __launch_bounds__(256) void zero_holes(__hip_bfloat16* __restrict__ buf)
{
    const int i = blockIdx.x * 256 + threadIdx.x;   // 16*220*C exact
    const int c = i % C;
    const int p = i / C;
    const int bt = p / 220, fp = p % 220;
    int oh, ow;
    if (fp < 56)       { oh = 0;        ow = fp; }
    else if (fp < 112) { oh = 55;       ow = fp - 56; }
    else if (fp < 166) { oh = fp - 111; ow = 0; }
    else               { oh = fp - 165; ow = 55; }
    const int g = c / GS;
    const int ih = oh - SGN * shift_h(g);
    const int iw = ow - SGN * shift_w(g);
    if ((unsigned)ih >= 56u || (unsigned)iw >= 56u)
        buf[((size_t)(bt * HWIMG + oh * 56 + ow)) * C + c] = __float2bfloat16(0.0f);
}

// ---- prep: x fp32 -> bf16 ---------------------------------------------------
__global__ __launch_bounds__(256) void cvt_x(const float4* __restrict__ x,
                                             __hip_bfloat16* __restrict__ xb)
{
    int i = blockIdx.x * 256 + threadIdx.x;
    float4 v = x[i];
    __hip_bfloat16 b0 = __float2bfloat16(v.x);
    __hip_bfloat16 b1 = __float2bfloat16(v.y);
    __hip_bfloat16 b2 = __float2bfloat16(v.z);
    __hip_bfloat16 b3 = __float2bfloat16(v.w);
    uint2 o;
    o.x = (uint)*(ushort*)&b0 | ((uint)*(ushort*)&b1 << 16);
    o.y = (uint)*(ushort*)&b2 | ((uint)*(ushort*)&b3 << 16);
    *(uint2*)&xb[(size_t)i * 4] = o;
}

// ---- prep: transpose + convert the 4 weight matrices to bf16 Bt layout -----
__global__ __launch_bounds__(256) void prep_w(
    const float* __restrict__ fcw,  const float* __restrict__ fc1w,
    const float* __restrict__ fc2w, const float* __restrict__ projw,
    __hip_bfloat16* __restrict__ fcwT, __hip_bfloat16* __restrict__ fc1T,
    __hip_bfloat16* __restrict__ fc2T, __hip_bfloat16* __restrict__ projT)
{
    int i = blockIdx.x * 256 + threadIdx.x;
    if (i < 524288) {                       // fc_w [512,1024] -> [1024,512]
        int n = i >> 9, k = i & 511;
        fcwT[i] = __float2bfloat16(fcw[k * 1024 + n]);
    } else if (i < 1048576) {               // fc1_w [1024,512] -> [512,1024]
        int j = i - 524288;
        int n = j >> 10, k = j & 1023;
        fc1T[j] = __float2bfloat16(fc1w[k * 512 + n]);
    } else if (i < 1572864) {               // fc2_w [1024,512] -> [512,1024]
        int j = i - 1048576;
        int n = j >> 10, k = j & 1023;
        fc2T[j] = __float2bfloat16(fc2w[k * 512 + n]);
    } else if (i < 1835008) {               // proj_w [512,512] -> [512,512]
        int j = i - 1572864;
        int n = j >> 9, k = j & 511;
        projT[j] = __float2bfloat16(projw[k * 512 + n]);
    }
}

// ---- tiny squeeze-excite MLP + pairwise softmax, fp32 exact ----------------
__global__ __launch_bounds__(256) void tiny_mlp(
    const float* __restrict__ s0, const float* __restrict__ s1,
    const float* __restrict__ rw1_w, const float* __restrict__ rw1_b,
    const float* __restrict__ rw2_w, const float* __restrict__ rw2_b,
    float* __restrict__ a0, float* __restrict__ a1)
{
    __shared__ float mean[1024];   // [2][512]
    __shared__ float z[256];       // [2][128]
    __shared__ float av[2048];     // [2][1024]
    const int t = threadIdx.x;
    for (int i = t; i < 1024; i += 256)
        mean[i] = (s0[i] + s1[i]) * (1.0f / 25088.0f);
    __syncthreads();
    {
        const int b = t >> 7, j = t & 127;
        float acc = rw1_b[j];
        for (int cc = 0; cc < 512; cc++)
            acc += mean[b * 512 + cc] * rw1_w[cc * 128 + j];
        z[t] = gelu_exact(acc);
    }
    __syncthreads();
    for (int i = t; i < 2048; i += 256) {
        const int b = i >> 10, o = i & 1023;
        float acc = rw2_b[o];
        for (int j = 0; j < 128; j++)
            acc += z[b * 128 + j] * rw2_w[j * 1024 + o];
        av[i] = acc;
    }
    __syncthreads();
    for (int i = t; i < 1024; i += 256) {
        const int b = i >> 9, cc = i & 511;
        const float x0 = av[b * 1024 + 2 * cc];
        const float x1 = av[b * 1024 + 2 * cc + 1];
        const float m = fmaxf(x0, x1);
        const float e0 = expf(x0 - m), e1 = expf(x1 - m);
        const float inv = 1.0f / (e0 + e1);
        a0[i] = e0 * inv;
        a1[i] = e1 * inv;
    }
}

// ---- hw = hs*a0 + w*a1 (shift-free, 8 channels / thread) --------------------
__device__ __forceinline__ float bf_lo(uint u) { return __uint_as_float(u << 16); }
__device__ __forceinline__ float bf_hi(uint u) { return __uint_as_float(u & 0xffff0000u); }
__device__ __forceinline__ uint pack_bf2(float lo, float hi) {
    __hip_bfloat16 a = __float2bfloat16(lo), b = __float2bfloat16(hi);
    return (uint)*(ushort*)&a | ((uint)*(ushort*)&b << 16);
}

__global__ __launch_bounds__(256) void combine(
    const uint4* __restrict__ hs4, const uint4* __restrict__ w4,
    const float* __restrict__ a0, const float* __restrict__ a1,
    uint4* __restrict__ hw4)
{
    const int i = blockIdx.x * 256 + threadIdx.x;   // 3,211,264 exact
    const int ck = i & 63;                          // 8-channel chunk
    const int tok = i >> 6;
    const int b = (tok >= 25088) ? 1 : 0;
    const float4* A0 = (const float4*)&a0[b * 512 + ck * 8];
    const float4* A1 = (const float4*)&a1[b * 512 + ck * 8];
    const float4 s0l = A0[0], s0h = A0[1];
    const float4 s1l = A1[0], s1h = A1[1];
    const uint4 h = hs4[i], w = w4[i];
    uint4 o;
    o.x = pack_bf2(bf_lo(h.x) * s0l.x + bf_lo(w.x) * s1l.x,
                   bf_hi(h.x) * s0l.y + bf_hi(w.x) * s1l.y);
    o.y = pack_bf2(bf_lo(h.y) * s0l.z + bf_lo(w.y) * s1l.z,
                   bf_hi(h.y) * s0l.w + bf_hi(w.y) * s1l.w);
    o.z = pack_bf2(bf_lo(h.z) * s0h.x + bf_lo(w.z) * s1h.x,
                   bf_hi(h.z) * s0h.y + bf_hi(w.z) * s1h.y);
    o.w = pack_bf2(bf_lo(h.w) * s0h.z + bf_lo(w.w) * s1h.z,
                   bf_hi(h.w) * s0h.w + bf_hi(w.w) * s1h.w);
    hw4[i] = o;
}

// ---------------------------------------------------------------------------
extern "C" void kernel_launch(void* const* d_in, const int* in_sizes, int n_in,
                              void* d_out, int out_size, void* d_ws, size_t ws_size,
                              hipStream_t stream)
{
    const float* x      = (const float*)d_in[0];
    const float* fc_w   = (const float*)d_in[1];
    const float* fc_b   = (const float*)d_in[2];
    const float* fc1_w  = (const float*)d_in[3];
    const float* fc1_b  = (const float*)d_in[4];
    const float* fc2_w  = (const float*)d_in[5];
    const float* fc2_b  = (const float*)d_in[6];
    const float* rw1_w  = (const float*)d_in[7];
    const float* rw1_b  = (const float*)d_in[8];
    const float* rw2_w  = (const float*)d_in[9];
    const float* rw2_b  = (const float*)d_in[10];
    const float* proj_w = (const float*)d_in[11];
    const float* proj_b = (const float*)d_in[12];

    uint8_t* ws = (uint8_t*)d_ws;
    __hip_bfloat16* xh  = (__hip_bfloat16*)(ws);                    // [N,1024] bf16, later hw
    __hip_bfloat16* xb  = (__hip_bfloat16*)(ws + 102760448);        // [N,512] bf16, later hs
    uint8_t* wt         = ws + 102760448 + 51380224;
    __hip_bfloat16* fcwT  = (__hip_bfloat16*)(wt);
    __hip_bfloat16* fc1T  = fcwT + 524288;
    __hip_bfloat16* fc2T  = fc1T + 524288;
    __hip_bfloat16* projT = fc2T + 524288;
    float* s0 = (float*)(wt + 3670016);
    float* s1 = s0 + 1024;
    float* a0 = s1 + 1024;
    float* a1 = a0 + 1024;

    __hip_bfloat16* wbuf = (__hip_bfloat16*)d_out;  // [N,512]  bf16 (dead after combine)
    __hip_bfloat16* hs   = xb;                      // [N,512]  bf16 (xb dead after GEMM1)
    __hip_bfloat16* hw   = xh;                      // [N,512]  bf16 (xh dead after GEMM3)

    hipMemsetAsync(s0, 0, 8192, stream);            // zero s0,s1

    cvt_x<<<25088, 256, 0, stream>>>((const float4*)x, xb);
    prep_w<<<7168, 256, 0, stream>>>(fc_w, fc1_w, fc2_w, proj_w, fcwT, fc1T, fc2T, projT);

    // GEMM1: xh = gelu(xb@fc_w+b) (plain store; shift gathered by GEMM2)
    gemm_bt<1, false><<<dim3(8, 392), 256, 0, stream>>>(
        xb, fcwT, fc_b, xh, nullptr, 1024, 512);
    // hs boundary holes (hs aliases xb -> must run after GEMM1)
    zero_holes<512, 57, -1><<<7040, 256, 0, stream>>>(hs);
    // GEMM2: hs = inv-shift scatter of gelu(SHIFT(xh)@fc1_w+b); fused s0
    gemm_bt<2, true><<<dim3(4, 392), 256, 0, stream>>>(
        xh, fc1T, fc1_b, hs, s0, 512, 1024);
    // GEMM3: w = gelu(xh@fc2_w+b) -> d_out; fused s1
    gemm_bt<3, false><<<dim3(4, 392), 256, 0, stream>>>(
        xh, fc2T, fc2_b, wbuf, s1, 512, 1024);
    // tiny MLP + softmax -> a0,a1
    tiny_mlp<<<1, 256, 0, stream>>>(s0, s1, rw1_w, rw1_b, rw2_w, rw2_b, a0, a1);
    // hw = hs*a0 + w*a1 -> xh region
    combine<<<12544, 256, 0, stream>>>((const uint4*)hs, (const uint4*)wbuf, a0, a1, (uint4*)hw);
    // GEMM4: out = hw @ proj_w + proj_b, fp32 -> d_out
    gemm_bt<0, false><<<dim3(4, 392), 256, 0, stream>>>(
        hw, projT, proj_b, d_out, nullptr, 512, 512);
}